// Round 13
// baseline (1007.512 us; speedup 1.0000x reference)
//
#include <hip/hip_runtime.h>
#include <hip/hip_bf16.h>
#include <cstdint>

#define B_ 512
#define T_ 48
#define N_ 62
#define F_ 5
#define E_ 496
#define H_ 512
#define NF_ 310      // N*F
#define SEQP 320     // padded seq row (310 -> 320)
#define KPAD 832     // 320 + 512
#define G4 2048      // 4*H
#define EPS_ 1e-5f
#define TC 12        // t-steps per cheb block (4 chunks)
#define LSTR 72      // LDS row stride in shorts

typedef __attribute__((ext_vector_type(8))) short short8;
typedef __attribute__((ext_vector_type(4))) short s16x4;
typedef __attribute__((ext_vector_type(4))) float f32x4;

__device__ __forceinline__ float sigm(float x)  { return 1.f / (1.f + __expf(-x)); }
__device__ __forceinline__ float tanhf_(float x){ return 2.f / (1.f + __expf(-2.f*x)) - 1.f; }

__device__ __forceinline__ short f2b(float v) {   // f32 -> bf16 bits, RN-even
  unsigned int u = __builtin_bit_cast(unsigned int, v);
  unsigned int r = (u + 0x7fffu + ((u >> 16) & 1u)) >> 16;
  return (short)r;
}
__device__ __forceinline__ float b2f(short s) {
  unsigned int u = ((unsigned int)(unsigned short)s) << 16;
  return __builtin_bit_cast(float, u);
}

__device__ __forceinline__ void dma16(const void* g, void* l) {
  __builtin_amdgcn_global_load_lds(
      (const __attribute__((address_space(1))) unsigned int*)g,
      (__attribute__((address_space(3))) unsigned int*)l, 16, 0, 0);
}

// ============ ChebConv K=3 via MFMA + BN partial stats; block = (graph, 12-t chunk) ============
__global__ __launch_bounds__(512) void k_cheb(
    const float* __restrict__ x, const int* __restrict__ esrc, const int* __restrict__ edst,
    const float* __restrict__ ew, const float* __restrict__ Wc, const float* __restrict__ bc,
    float* __restrict__ cheb, float* __restrict__ bps, float* __restrict__ bpq)
{
  __shared__ __align__(16) short SH[4*64*LSTR];
  __shared__ float dinv[N_];
  short* Lb  = SH;
  short* Xt  = SH + 64*LSTR;
  short* T1t = SH + 2*64*LSTR;
  short* T2t = SH + 3*64*LSTR;
  float* Af  = (float*)T1t;

  const int tid = threadIdx.x;
  const int b = blockIdx.x;
  const int t0 = blockIdx.y * TC;

  for (int i = tid; i < 2*64*LSTR; i += 512) SH[i] = 0;
  for (int i = tid; i < N_*N_;     i += 512) Af[i] = 0.f;
  __syncthreads();

  for (int e = tid; e < E_; e += 512)
    atomicAdd(&Af[edst[b*E_ + e]*N_ + esrc[b*E_ + e]], ew[b*E_ + e]);
  for (int i = tid; i < TC*NF_; i += 512) {
    int tl = i / NF_, nf = i - tl*NF_;
    float v = x[((size_t)b*T_ + t0 + tl)*NF_ + nf];
    int n = nf / F_, f = nf - n*F_;
    Xt[(tl*F_ + f)*LSTR + n] = f2b(v);
  }
  __syncthreads();

  if (tid < N_) {
    float s = 0.f;
    for (int m = 0; m < N_; ++m) s += Af[tid*N_ + m];
    dinv[tid] = (s > 0.f) ? rsqrtf(s) : 0.f;
  }
  __syncthreads();
  for (int i = tid; i < N_*N_; i += 512) {
    int n = i / N_, m = i - n*N_;
    Lb[n*LSTR + m] = f2b(-dinv[n] * Af[i] * dinv[m]);
  }
  __syncthreads();

  const int w = tid >> 6, lane = tid & 63, l16 = lane & 15, lhi = lane >> 4;
  const int mt = w >> 1;
  const int nt = (w & 1) * 2;

  {
    f32x4 acc0 = {0.f,0.f,0.f,0.f}, acc1 = acc0;
    #pragma unroll
    for (int kc = 0; kc < 2; ++kc) {
      short8 a  = *(const short8*)(Lb + (mt*16 + l16)*LSTR + kc*32 + lhi*8);
      short8 b0 = *(const short8*)(Xt + ((nt  )*16 + l16)*LSTR + kc*32 + lhi*8);
      short8 b1 = *(const short8*)(Xt + ((nt+1)*16 + l16)*LSTR + kc*32 + lhi*8);
      acc0 = __builtin_amdgcn_mfma_f32_16x16x32_bf16(a, b0, acc0, 0, 0, 0);
      acc1 = __builtin_amdgcn_mfma_f32_16x16x32_bf16(a, b1, acc1, 0, 0, 0);
    }
    #pragma unroll
    for (int i = 0; i < 2; ++i) {
      f32x4 acc = i ? acc1 : acc0;
      int c = (nt+i)*16 + l16, n = mt*16 + lhi*4;
      s16x4 pk;
      #pragma unroll
      for (int r = 0; r < 4; ++r) pk[r] = f2b(acc[r]);
      *(s16x4*)(T1t + c*LSTR + n) = pk;
    }
  }
  __syncthreads();

  {
    f32x4 acc0 = {0.f,0.f,0.f,0.f}, acc1 = acc0;
    #pragma unroll
    for (int kc = 0; kc < 2; ++kc) {
      short8 a  = *(const short8*)(Lb + (mt*16 + l16)*LSTR + kc*32 + lhi*8);
      short8 b0 = *(const short8*)(T1t + ((nt  )*16 + l16)*LSTR + kc*32 + lhi*8);
      short8 b1 = *(const short8*)(T1t + ((nt+1)*16 + l16)*LSTR + kc*32 + lhi*8);
      acc0 = __builtin_amdgcn_mfma_f32_16x16x32_bf16(a, b0, acc0, 0, 0, 0);
      acc1 = __builtin_amdgcn_mfma_f32_16x16x32_bf16(a, b1, acc1, 0, 0, 0);
    }
    #pragma unroll
    for (int i = 0; i < 2; ++i) {
      f32x4 acc = i ? acc1 : acc0;
      int c = (nt+i)*16 + l16, n = mt*16 + lhi*4;
      s16x4 xv = *(const s16x4*)(Xt + c*LSTR + n);
      s16x4 pk;
      #pragma unroll
      for (int r = 0; r < 4; ++r) pk[r] = f2b(2.f*acc[r] - b2f(xv[r]));
      *(s16x4*)(T2t + c*LSTR + n) = pk;
    }
  }
  __syncthreads();

  const int pair = tid >> 2, q = tid & 3;
  if (pair < TC*F_) {
    const int tl = pair / F_, g = pair - (pair/F_)*F_;
    const int t = t0 + tl;
    float w0[5], w1[5], w2[5];
    #pragma unroll
    for (int ff = 0; ff < 5; ++ff) {
      w0[ff] = Wc[t*75 +      ff*5 + g];
      w1[ff] = Wc[t*75 + 25 + ff*5 + g];
      w2[ff] = Wc[t*75 + 50 + ff*5 + g];
    }
    const float bias = bc[t*F_ + g];
    float ss = 0.f, qq = 0.f;
    float* chout = cheb + ((size_t)t*B_ + b)*NF_;
    #pragma unroll
    for (int grp = 0; grp < 4; ++grp) {
      int n4 = grp*16 + q*4;
      float o[4] = {bias, bias, bias, bias};
      #pragma unroll
      for (int ff = 0; ff < 5; ++ff) {
        int c = tl*F_ + ff;
        s16x4 xv = *(const s16x4*)(Xt  + c*LSTR + n4);
        s16x4 v1 = *(const s16x4*)(T1t + c*LSTR + n4);
        s16x4 v2 = *(const s16x4*)(T2t + c*LSTR + n4);
        #pragma unroll
        for (int i = 0; i < 4; ++i)
          o[i] += b2f(xv[i])*w0[ff] + b2f(v1[i])*w1[ff] + b2f(v2[i])*w2[ff];
      }
      #pragma unroll
      for (int i = 0; i < 4; ++i) {
        int n = n4 + i;
        if (n < N_) { chout[n*F_ + g] = o[i]; ss += o[i]; qq += o[i]*o[i]; }
      }
    }
    ss += __shfl_down(ss, 2, 4); ss += __shfl_down(ss, 1, 4);
    qq += __shfl_down(qq, 2, 4); qq += __shfl_down(qq, 1, 4);
    if (q == 0) { bps[(t*F_ + g)*B_ + b] = ss; bpq[(t*F_ + g)*B_ + b] = qq; }
  }
}

// ============ finalize BN scale/shift per (t,f) ============
__global__ __launch_bounds__(64) void k_bnfin(
    const float* __restrict__ bps, const float* __restrict__ bpq,
    const float* __restrict__ bng, const float* __restrict__ bnb,
    float* __restrict__ alpha, float* __restrict__ bet)
{
  const int tf = blockIdx.x;
  const int lane = threadIdx.x;
  float s = 0.f, q = 0.f;
  for (int i = lane; i < B_; i += 64) { s += bps[tf*B_ + i]; q += bpq[tf*B_ + i]; }
  #pragma unroll
  for (int off = 32; off; off >>= 1) { s += __shfl_down(s, off); q += __shfl_down(q, off); }
  if (lane == 0) {
    const float cnt = (float)(B_*N_);
    float mu = s / cnt;
    float var = q / cnt - mu*mu;
    float al = bng[tf] * rsqrtf(var + EPS_);
    alpha[tf] = al;
    bet[tf] = bnb[tf] - mu*al;
  }
}

// ============ BN apply + pack to bf16 PRE-SWIZZLED sequence [t][b][320] ============
__global__ __launch_bounds__(256) void k_seq(
    const float* __restrict__ cheb, const float* __restrict__ alpha, const float* __restrict__ bet,
    __hip_bfloat16* __restrict__ seqb)
{
  int idx = blockIdx.x*256 + threadIdx.x;     // T*B*320
  int kp = idx % SEQP;                        // physical position
  int tb = idx / SEQP;
  int b = tb & (B_-1), t = tb >> 9;
  int sl = (kp >> 3) ^ (b & 7);               // logical slot
  int kl = sl*8 + (kp & 7);                   // logical element
  float v = 0.f;
  if (kl < NF_) v = cheb[(size_t)tb*NF_ + kl] * alpha[t*F_ + (kl % F_)] + bet[t*F_ + (kl % F_)];
  seqb[idx] = __float2bfloat16(v);
}

// ============ weight prep: gate-interleaved rows j' = jh*4 + gate; K = [seq-logical|pad|h] ============
__global__ __launch_bounds__(256) void k_prep(
    const float* __restrict__ Wih, const float* __restrict__ Whh,
    const float* __restrict__ bih, const float* __restrict__ bhh,
    __hip_bfloat16* __restrict__ Wcat, float* __restrict__ biasr)
{
  const int jp = blockIdx.x;
  const int g = jp & 3, jh = jp >> 2;
  const int jo = g*H_ + jh;
  for (int k = threadIdx.x; k < KPAD; k += 256) {
    float v = 0.f;
    if (k < NF_) v = Wih[(size_t)jo*NF_ + k];
    else if (k >= SEQP) v = Whh[(size_t)jo*H_ + (k - SEQP)];
    Wcat[(size_t)jp*KPAD + k] = __float2bfloat16(v);
  }
  if (threadIdx.x == 0) biasr[jp] = bih[jo] + bhh[jo];
}

// ============ persistent LSTM v8: 1024-thr blocks, 8-block groups (fan-out 8) ============
// 128 blocks x 1024 thr (16 waves, 4/SIMD). Block (rg=bid&15, jt=bid>>4, jt<8):
// 32 b-rows x 256 j'-cols. Groups of 8 blocks exchange h via write-once swizzled
// hbuf (sc0 sc1 -> LLC) + per-producer flag words; 8-lane parallel poll.
// gl overlays lh (dead after MFH) -> static LDS 52 KB.
#define WOP(M)  M(0) M(1) M(2) M(3) M(4) M(5) M(6) M(7) M(8) M(9) M(10) M(11) M(12) M(13) \
                M(14) M(15) M(16) M(17) M(18) M(19) M(20) M(21) M(22) M(23) M(24) M(25)
#define WSEQ(M) M(0) M(1) M(2) M(3) M(4) M(5) M(6) M(7) M(8) M(9)
#define WHP(M)  M(10) M(11) M(12) M(13) M(14) M(15) M(16) M(17) M(18) M(19) M(20) M(21) \
                M(22) M(23) M(24) M(25)

#define DECLW(i) short8 wv##i;
#define LOADW(i) wv##i = *(const short8*)(wp + (i)*32); \
                 asm volatile("" : "+v"(wv##i));
#define MFS(i) { const int ph = (((i)*4 + lhi) ^ key)*8; \
                 short8 x0 = *(const short8*)(lseq + rs0*SEQP + ph); \
                 short8 x1 = *(const short8*)(lseq + rs1*SEQP + ph); \
                 a0 = __builtin_amdgcn_mfma_f32_16x16x32_bf16(x0, wv##i, a0, 0, 0, 0); \
                 a1 = __builtin_amdgcn_mfma_f32_16x16x32_bf16(x1, wv##i, a1, 0, 0, 0); }
#define MFH(i) { const int ph = ((((i)-10)*4 + lhi) ^ key)*8; \
                 short8 x0 = *(const short8*)(lh + rs0*H_ + ph); \
                 short8 x1 = *(const short8*)(lh + rs1*H_ + ph); \
                 a0 = __builtin_amdgcn_mfma_f32_16x16x32_bf16(x0, wv##i, a0, 0, 0, 0); \
                 a1 = __builtin_amdgcn_mfma_f32_16x16x32_bf16(x1, wv##i, a1, 0, 0, 0); }

__global__ __launch_bounds__(1024, 1) void k_lstm(
    const __hip_bfloat16* __restrict__ seqb,   // (T, B, 320) bf16, slot-swizzled
    const __hip_bfloat16* __restrict__ Wcat,   // (2048, 832) gate-interleaved
    const float* __restrict__ biasr,           // (2048)
    __hip_bfloat16* __restrict__ hb,           // (T, B, 512) bf16, slot-swizzled, write-once
    unsigned int* __restrict__ bar)            // (16*64) zeroed, rg-major flag words
{
  __shared__ __align__(16) short lh[32*H_];    // 32 KB: h panel (gl overlays after MFH)
  __shared__ __align__(16) short lseq[32*SEQP];// 20 KB: seq panel
  float (*gl)[256] = (float (*)[256])lh;       // 32x256 f32 = 32 KB overlay (exact)

  const int tid = threadIdx.x;
  const int bid = blockIdx.x;
  const int rg = bid & 15, jt = bid >> 4;      // jt in 0..7
  const int b0 = rg*32, j0 = jt*256;
  const int w = tid >> 6, lane = tid & 63, l16 = lane & 15, lhi = lane >> 4;
  const int key = l16 & 7;
  const int rs0 = l16, rs1 = l16 + 16;

  // ---- pin this wave's 26 weight fragments (col-tile = j0 + w*16, w 0..15) ----
  const short* wp = (const short*)Wcat + (size_t)(j0 + w*16 + l16)*KPAD + lhi*8;
  WOP(DECLW)
  WOP(LOADW)

  // cell mapping: 32 rows x 64 units; thread -> (crow = tid>>5, u2 = tid&31, 2 units)
  const int crow = tid >> 5, u2 = tid & 31;
  const int hrow = b0 + crow;
  float cc0 = 0.f, cc1 = 0.f;
  f32x4 biaA = *(const f32x4*)(biasr + j0 + u2*8 + 0);
  f32x4 biaB = *(const f32x4*)(biasr + j0 + u2*8 + 4);
  const int hslot = (jt*8 + (u2 >> 2)) ^ (hrow & 7);
  const int hoff = hslot*8 + (u2 & 3)*2;

  const char* gseq = (const char*)seqb;
  const char* ghb  = (const char*)hb;
  char* lsc = (char*)lseq;
  char* lhc = (char*)lh;

  // prologue: stage seq(0): 20 x 1KB chunks over 16 waves
  {
    const char* gs = gseq + ((size_t)b0)*640;
    #pragma unroll
    for (int i = 0; i < 2; ++i) {
      int c = w + i*16;
      if (c < 20) dma16(gs + c*1024 + lane*16, lsc + c*1024);
    }
  }

  #pragma unroll 1
  for (int t = 0; t < T_; ++t) {
    // ---- wait for all 8 producers' flags >= t (parallel 8-lane probe) ----
    if (t > 0 && w == 0) {
      for (;;) {
        unsigned int v = 0xFFFFFFFFu;
        if (lane < 8)
          v = __hip_atomic_load(&bar[rg*64 + lane], __ATOMIC_RELAXED,
                                __HIP_MEMORY_SCOPE_AGENT);
        if (__all(v >= (unsigned int)t)) break;
        __builtin_amdgcn_s_sleep(1);
      }
    }
    __syncthreads();                           // (A) seq(t) staged; flags seen; prefetch drained

    if (t > 0) {                               // stage h(t-1): 32 x 1KB rows, 2 dma16/wave
      const char* gh = ghb + ((size_t)(t-1)*B_ + b0)*1024;
      #pragma unroll
      for (int i = 0; i < 2; ++i) {
        int c = w*2 + i;
        dma16(gh + c*1024 + lane*16, lhc + c*1024);
      }
    }

    // seq-part MFMAs (overlap h DMA)
    f32x4 a0 = {0.f,0.f,0.f,0.f}, a1 = a0;
    WSEQ(MFS)

    if (t > 0) {
      __syncthreads();                         // (B) h DMA drained (all waves)
      WHP(MFH)
    }
    __syncthreads();                           // (C) lh reads done -> gl overlay safe

    #pragma unroll
    for (int r = 0; r < 4; ++r) {
      gl[     lhi*4 + r][w*16 + l16] = a0[r];
      gl[16 + lhi*4 + r][w*16 + l16] = a1[r];
    }
    __syncthreads();                           // (D) gl visible

    // cell update: 2 hidden units per thread
    {
      f32x4 ga = *(const f32x4*)(&gl[crow][u2*8 + 0]);
      f32x4 gb = *(const f32x4*)(&gl[crow][u2*8 + 4]);
      float iv0 = sigm(ga[0]+biaA[0]), fv0 = sigm(ga[1]+biaA[1]);
      float gv0 = tanhf_(ga[2]+biaA[2]), ov0 = sigm(ga[3]+biaA[3]);
      cc0 = fv0*cc0 + iv0*gv0;
      float h0 = ov0*tanhf_(cc0);
      float iv1 = sigm(gb[0]+biaB[0]), fv1 = sigm(gb[1]+biaB[1]);
      float gv1 = tanhf_(gb[2]+biaB[2]), ov1 = sigm(gb[3]+biaB[3]);
      cc1 = fv1*cc1 + iv1*gv1;
      float h1 = ov1*tanhf_(cc1);
      unsigned int d0;
      asm("v_cvt_pk_bf16_f32 %0, %1, %2" : "=v"(d0) : "v"(h0), "v"(h1));
      short* dst = (short*)hb + ((size_t)t*B_ + hrow)*H_ + hoff;
      asm volatile("global_store_dword %0, %1, off sc0 sc1"
                   :: "v"(dst), "v"(d0) : "memory");
    }
    __syncthreads();                           // (E) h stores drained (gl reads done too)

    if (t < T_ - 1) {
      if (tid == 0)                            // own flag word: plain store, no RMW
        __hip_atomic_store(&bar[rg*64 + jt], (unsigned int)(t+1),
                           __ATOMIC_RELAXED, __HIP_MEMORY_SCOPE_AGENT);
      const char* gs = gseq + ((size_t)(t+1)*B_ + b0)*640;
      #pragma unroll
      for (int i = 0; i < 2; ++i) {            // prefetch seq(t+1) OFF the critical path
        int c = w + i*16;
        if (c < 20) dma16(gs + c*1024 + lane*16, lsc + c*1024);
      }
    }
  }
}

// ============ BN1 partial stats over (B,H) per t — order-independent, swizzle-agnostic ============
__global__ __launch_bounds__(256) void k_bn1part(
    const __hip_bfloat16* __restrict__ hb, float* __restrict__ bn1s, float* __restrict__ bn1q)
{
  const int t = blockIdx.x, ch = blockIdx.y, tid = threadIdx.x;
  const short* base = (const short*)hb + ((size_t)t*B_ + ch*64)*H_;
  float s = 0.f, q = 0.f;
  for (int i = tid; i < 64*H_/8; i += 256) {
    short8 v8 = *(const short8*)(base + (i>>6)*H_ + (i&63)*8);
    #pragma unroll
    for (int j = 0; j < 8; ++j) { float v = b2f(v8[j]); s += v; q += v*v; }
  }
  __shared__ float rs[256], rq[256];
  rs[tid] = s; rq[tid] = q;
  __syncthreads();
  for (int o = 128; o; o >>= 1) {
    if (tid < o) { rs[tid] += rs[tid+o]; rq[tid] += rq[tid+o]; }
    __syncthreads();
  }
  if (tid == 0) { bn1s[t*8 + ch] = rs[0]; bn1q[t*8 + ch] = rq[0]; }
}

// ============ head: fold BN1 + (B, T*H) @ Wl^T + bl — unswizzles hbuf slots ============
__global__ __launch_bounds__(256) void k_head(
    const __hip_bfloat16* __restrict__ hb, const float* __restrict__ bn1s,
    const float* __restrict__ bn1q, const float* __restrict__ g1,
    const float* __restrict__ be1, const float* __restrict__ Wl,
    const float* __restrict__ bl, float* __restrict__ out)
{
  const int b = blockIdx.x, tid = threadIdx.x;
  __shared__ float al1[T_], bt1[T_];
  if (tid < T_) {
    float s = 0.f, q = 0.f;
    #pragma unroll
    for (int ch = 0; ch < 8; ++ch) { s += bn1s[tid*8 + ch]; q += bn1q[tid*8 + ch]; }
    const float cnt = (float)(B_*H_);
    float mu = s / cnt, var = q / cnt - mu*mu;
    float al = g1[tid] * rsqrtf(var + EPS_);
    al1[tid] = al; bt1[tid] = be1[tid] - mu*al;
  }
  __syncthreads();
  float a0 = 0.f, a1 = 0.f, a2 = 0.f;
  const short* hbs = (const short*)hb;
  for (int p8 = tid; p8 < T_*(H_/8); p8 += 256) {
    const int t = p8 >> 6, p = p8 & 63;
    short8 v8 = *(const short8*)(hbs + ((size_t)t*B_ + b)*H_ + p*8);
    const int wi = t*H_ + ((p ^ (b & 7)) << 3);
    #pragma unroll
    for (int j = 0; j < 8; ++j) {
      float yn = b2f(v8[j])*al1[t] + bt1[t];
      a0 = fmaf(yn, Wl[wi + j],            a0);
      a1 = fmaf(yn, Wl[T_*H_ + wi + j],    a1);
      a2 = fmaf(yn, Wl[2*T_*H_ + wi + j],  a2);
    }
  }
  __shared__ float red[256];
  red[tid] = a0; __syncthreads();
  for (int o = 128; o; o >>= 1) { if (tid < o) red[tid] += red[tid+o]; __syncthreads(); }
  if (!tid) out[b*3 + 0] = red[0] + bl[0];
  __syncthreads();
  red[tid] = a1; __syncthreads();
  for (int o = 128; o; o >>= 1) { if (tid < o) red[tid] += red[tid+o]; __syncthreads(); }
  if (!tid) out[b*3 + 1] = red[0] + bl[1];
  __syncthreads();
  red[tid] = a2; __syncthreads();
  for (int o = 128; o; o >>= 1) { if (tid < o) red[tid] += red[tid+o]; __syncthreads(); }
  if (!tid) out[b*3 + 2] = red[0] + bl[2];
}

extern "C" void kernel_launch(void* const* d_in, const int* in_sizes, int n_in,
                              void* d_out, int out_size, void* d_ws, size_t ws_size,
                              hipStream_t stream)
{
  (void)in_sizes; (void)n_in; (void)out_size;
  const float* x   = (const float*)d_in[0];
  const int* esrc  = (const int*)d_in[1];
  const int* edst  = (const int*)d_in[2];
  const float* ew  = (const float*)d_in[3];
  const float* Wc  = (const float*)d_in[4];
  const float* bc  = (const float*)d_in[5];
  const float* bng = (const float*)d_in[6];
  const float* bnb = (const float*)d_in[7];
  const float* Wih = (const float*)d_in[8];
  const float* Whh = (const float*)d_in[9];
  const float* bih = (const float*)d_in[10];
  const float* bhh = (const float*)d_in[11];
  const float* g1  = (const float*)d_in[12];
  const float* be1 = (const float*)d_in[13];
  const float* Wl  = (const float*)d_in[14];
  const float* bl  = (const float*)d_in[15];
  float* out = (float*)d_out;

  char* ws = (char*)d_ws;
  size_t off = 0;
  auto alloc = [&](size_t bytes) {
    void* p = ws + off;
    off += (bytes + 255) & ~(size_t)255;
    return p;
  };
  float* cheb = (float*)alloc(sizeof(float)*(size_t)T_*B_*NF_);
  float* bps  = (float*)alloc(sizeof(float)*T_*F_*B_);
  float* bpq  = (float*)alloc(sizeof(float)*T_*F_*B_);
  float* alpha= (float*)alloc(sizeof(float)*T_*F_);
  float* bet  = (float*)alloc(sizeof(float)*T_*F_);
  __hip_bfloat16* seqb = (__hip_bfloat16*)alloc(sizeof(__hip_bfloat16)*(size_t)T_*B_*SEQP);
  __hip_bfloat16* Wcat = (__hip_bfloat16*)alloc(sizeof(__hip_bfloat16)*(size_t)G4*KPAD);
  float* biasr = (float*)alloc(sizeof(float)*G4);
  __hip_bfloat16* hbuf = (__hip_bfloat16*)alloc(sizeof(__hip_bfloat16)*(size_t)T_*B_*H_);
  float* bn1s = (float*)alloc(sizeof(float)*T_*8);
  float* bn1q = (float*)alloc(sizeof(float)*T_*8);
  unsigned int* bar = (unsigned int*)alloc(sizeof(unsigned int)*16*64);
  if (ws_size < off) return;   // ~76 MB — within proven budget

  (void)hipMemsetAsync(bar, 0, sizeof(unsigned int)*16*64, stream);

  k_cheb<<<dim3(B_, T_/TC), 512, 0, stream>>>(x, esrc, edst, ew, Wc, bc, cheb, bps, bpq);
  k_bnfin<<<T_*F_, 64, 0, stream>>>(bps, bpq, bng, bnb, alpha, bet);
  k_seq<<<(T_*B_*SEQP)/256, 256, 0, stream>>>(cheb, alpha, bet, seqb);
  k_prep<<<G4, 256, 0, stream>>>(Wih, Whh, bih, bhh, Wcat, biasr);

  k_lstm<<<128, 1024, 0, stream>>>(seqb, Wcat, biasr, hbuf, bar);

  k_bn1part<<<dim3(T_, 8), 256, 0, stream>>>(hbuf, bn1s, bn1q);
  k_head<<<B_, 256, 0, stream>>>(hbuf, bn1s, bn1q, g1, be1, Wl, bl, out);
}

// Round 14
// 246.486 us; speedup vs baseline: 4.0875x; 4.0875x over previous
//
#include <hip/hip_runtime.h>
#include <hip/hip_bf16.h>
#include <cstdint>

#define B_ 512
#define T_ 48
#define N_ 62
#define F_ 5
#define E_ 496
#define H_ 512
#define NF_ 310      // N*F
#define SEQP 320     // padded seq row (310 -> 320)
#define KPAD 832     // 320 + 512
#define G4 2048      // 4*H
#define EPS_ 1e-5f
#define TC 12        // t-steps per cheb block (4 chunks)
#define LSTR 72      // LDS row stride in shorts

typedef __attribute__((ext_vector_type(8))) short short8;
typedef __attribute__((ext_vector_type(4))) short s16x4;
typedef __attribute__((ext_vector_type(4))) float f32x4;

__device__ __forceinline__ float sigm(float x)  { return 1.f / (1.f + __expf(-x)); }
__device__ __forceinline__ float tanhf_(float x){ return 2.f / (1.f + __expf(-2.f*x)) - 1.f; }

__device__ __forceinline__ short f2b(float v) {   // f32 -> bf16 bits, RN-even
  unsigned int u = __builtin_bit_cast(unsigned int, v);
  unsigned int r = (u + 0x7fffu + ((u >> 16) & 1u)) >> 16;
  return (short)r;
}
__device__ __forceinline__ float b2f(short s) {
  unsigned int u = ((unsigned int)(unsigned short)s) << 16;
  return __builtin_bit_cast(float, u);
}

__device__ __forceinline__ void dma16(const void* g, void* l) {
  __builtin_amdgcn_global_load_lds(
      (const __attribute__((address_space(1))) unsigned int*)g,
      (__attribute__((address_space(3))) unsigned int*)l, 16, 0, 0);
}

// ============ fused: per-graph Lhat build (blocks 0..511) + weight prep (512..2559) ============
__global__ __launch_bounds__(256) void k_lapprep(
    const int* __restrict__ esrc, const int* __restrict__ edst, const float* __restrict__ ew,
    const float* __restrict__ Wih, const float* __restrict__ Whh,
    const float* __restrict__ bih, const float* __restrict__ bhh,
    __hip_bfloat16* __restrict__ lap,          // (B, 64, 64) bf16, zero-padded
    __hip_bfloat16* __restrict__ Wcat, float* __restrict__ biasr)
{
  const int bid = blockIdx.x;
  const int tid = threadIdx.x;
  __shared__ float Af[N_*N_];
  __shared__ float dinv[N_];

  if (bid < B_) {
    for (int i = tid; i < N_*N_; i += 256) Af[i] = 0.f;
    __syncthreads();
    for (int e = tid; e < E_; e += 256)
      atomicAdd(&Af[edst[bid*E_ + e]*N_ + esrc[bid*E_ + e]], ew[bid*E_ + e]);
    __syncthreads();
    if (tid < N_) {
      float s = 0.f;
      for (int m = 0; m < N_; ++m) s += Af[tid*N_ + m];
      dinv[tid] = (s > 0.f) ? rsqrtf(s) : 0.f;
    }
    __syncthreads();
    short* lp = (short*)lap + (size_t)bid*4096;
    for (int i = tid; i < 4096; i += 256) {
      int n = i >> 6, m = i & 63;
      float v = (n < N_ && m < N_) ? -dinv[n]*Af[n*N_ + m]*dinv[m] : 0.f;
      lp[i] = f2b(v);
    }
  } else {
    const int jp = bid - B_;                  // 0..2047
    const int g = jp & 3, jh = jp >> 2;
    const int jo = g*H_ + jh;
    for (int k = tid; k < KPAD; k += 256) {
      float v = 0.f;
      if (k < NF_) v = Wih[(size_t)jo*NF_ + k];
      else if (k >= SEQP) v = Whh[(size_t)jo*H_ + (k - SEQP)];
      Wcat[(size_t)jp*KPAD + k] = __float2bfloat16(v);
    }
    if (tid == 0) biasr[jp] = bih[jo] + bhh[jo];
  }
}

// ============ ChebConv K=3 via MFMA + BN partial stats; block = (graph, 12-t chunk) ============
// Lhat precomputed by k_lapprep — no A-build duplication.
__global__ __launch_bounds__(512) void k_cheb(
    const float* __restrict__ x, const __hip_bfloat16* __restrict__ lap,
    const float* __restrict__ Wc, const float* __restrict__ bc,
    float* __restrict__ cheb, float* __restrict__ bps, float* __restrict__ bpq)
{
  __shared__ __align__(16) short SH[4*64*LSTR];
  short* Lb  = SH;
  short* Xt  = SH + 64*LSTR;
  short* T1t = SH + 2*64*LSTR;
  short* T2t = SH + 3*64*LSTR;

  const int tid = threadIdx.x;
  const int b = blockIdx.x;
  const int t0 = blockIdx.y * TC;

  // load Lhat (8KB, one short8 per thread) + zero Xt
  {
    const short8* lp = (const short8*)((const short*)lap + (size_t)b*4096);
    short8 v = lp[tid];
    int n = tid >> 3, m = (tid & 7)*8;
    *(short8*)(Lb + n*LSTR + m) = v;
  }
  for (int i = tid; i < 64*LSTR; i += 512) Xt[i] = 0;
  __syncthreads();

  for (int i = tid; i < TC*NF_; i += 512) {
    int tl = i / NF_, nf = i - tl*NF_;
    float v = x[((size_t)b*T_ + t0 + tl)*NF_ + nf];
    int n = nf / F_, f = nf - n*F_;
    Xt[(tl*F_ + f)*LSTR + n] = f2b(v);
  }
  __syncthreads();

  const int w = tid >> 6, lane = tid & 63, l16 = lane & 15, lhi = lane >> 4;
  const int mt = w >> 1;
  const int nt = (w & 1) * 2;

  {
    f32x4 acc0 = {0.f,0.f,0.f,0.f}, acc1 = acc0;
    #pragma unroll
    for (int kc = 0; kc < 2; ++kc) {
      short8 a  = *(const short8*)(Lb + (mt*16 + l16)*LSTR + kc*32 + lhi*8);
      short8 b0 = *(const short8*)(Xt + ((nt  )*16 + l16)*LSTR + kc*32 + lhi*8);
      short8 b1 = *(const short8*)(Xt + ((nt+1)*16 + l16)*LSTR + kc*32 + lhi*8);
      acc0 = __builtin_amdgcn_mfma_f32_16x16x32_bf16(a, b0, acc0, 0, 0, 0);
      acc1 = __builtin_amdgcn_mfma_f32_16x16x32_bf16(a, b1, acc1, 0, 0, 0);
    }
    #pragma unroll
    for (int i = 0; i < 2; ++i) {
      f32x4 acc = i ? acc1 : acc0;
      int c = (nt+i)*16 + l16, n = mt*16 + lhi*4;
      s16x4 pk;
      #pragma unroll
      for (int r = 0; r < 4; ++r) pk[r] = f2b(acc[r]);
      *(s16x4*)(T1t + c*LSTR + n) = pk;
    }
  }
  __syncthreads();

  {
    f32x4 acc0 = {0.f,0.f,0.f,0.f}, acc1 = acc0;
    #pragma unroll
    for (int kc = 0; kc < 2; ++kc) {
      short8 a  = *(const short8*)(Lb + (mt*16 + l16)*LSTR + kc*32 + lhi*8);
      short8 b0 = *(const short8*)(T1t + ((nt  )*16 + l16)*LSTR + kc*32 + lhi*8);
      short8 b1 = *(const short8*)(T1t + ((nt+1)*16 + l16)*LSTR + kc*32 + lhi*8);
      acc0 = __builtin_amdgcn_mfma_f32_16x16x32_bf16(a, b0, acc0, 0, 0, 0);
      acc1 = __builtin_amdgcn_mfma_f32_16x16x32_bf16(a, b1, acc1, 0, 0, 0);
    }
    #pragma unroll
    for (int i = 0; i < 2; ++i) {
      f32x4 acc = i ? acc1 : acc0;
      int c = (nt+i)*16 + l16, n = mt*16 + lhi*4;
      s16x4 xv = *(const s16x4*)(Xt + c*LSTR + n);
      s16x4 pk;
      #pragma unroll
      for (int r = 0; r < 4; ++r) pk[r] = f2b(2.f*acc[r] - b2f(xv[r]));
      *(s16x4*)(T2t + c*LSTR + n) = pk;
    }
  }
  __syncthreads();

  const int pair = tid >> 2, q = tid & 3;
  if (pair < TC*F_) {
    const int tl = pair / F_, g = pair - (pair/F_)*F_;
    const int t = t0 + tl;
    float w0[5], w1[5], w2[5];
    #pragma unroll
    for (int ff = 0; ff < 5; ++ff) {
      w0[ff] = Wc[t*75 +      ff*5 + g];
      w1[ff] = Wc[t*75 + 25 + ff*5 + g];
      w2[ff] = Wc[t*75 + 50 + ff*5 + g];
    }
    const float bias = bc[t*F_ + g];
    float ss = 0.f, qq = 0.f;
    float* chout = cheb + ((size_t)t*B_ + b)*NF_;
    #pragma unroll
    for (int grp = 0; grp < 4; ++grp) {
      int n4 = grp*16 + q*4;
      float o[4] = {bias, bias, bias, bias};
      #pragma unroll
      for (int ff = 0; ff < 5; ++ff) {
        int c = tl*F_ + ff;
        s16x4 xv = *(const s16x4*)(Xt  + c*LSTR + n4);
        s16x4 v1 = *(const s16x4*)(T1t + c*LSTR + n4);
        s16x4 v2 = *(const s16x4*)(T2t + c*LSTR + n4);
        #pragma unroll
        for (int i = 0; i < 4; ++i)
          o[i] += b2f(xv[i])*w0[ff] + b2f(v1[i])*w1[ff] + b2f(v2[i])*w2[ff];
      }
      #pragma unroll
      for (int i = 0; i < 4; ++i) {
        int n = n4 + i;
        if (n < N_) { chout[n*F_ + g] = o[i]; ss += o[i]; qq += o[i]*o[i]; }
      }
    }
    ss += __shfl_down(ss, 2, 4); ss += __shfl_down(ss, 1, 4);
    qq += __shfl_down(qq, 2, 4); qq += __shfl_down(qq, 1, 4);
    if (q == 0) { bps[(t*F_ + g)*B_ + b] = ss; bpq[(t*F_ + g)*B_ + b] = qq; }
  }
}

// ============ finalize BN scale/shift per (t,f) ============
__global__ __launch_bounds__(64) void k_bnfin(
    const float* __restrict__ bps, const float* __restrict__ bpq,
    const float* __restrict__ bng, const float* __restrict__ bnb,
    float* __restrict__ alpha, float* __restrict__ bet)
{
  const int tf = blockIdx.x;
  const int lane = threadIdx.x;
  float s = 0.f, q = 0.f;
  for (int i = lane; i < B_; i += 64) { s += bps[tf*B_ + i]; q += bpq[tf*B_ + i]; }
  #pragma unroll
  for (int off = 32; off; off >>= 1) { s += __shfl_down(s, off); q += __shfl_down(q, off); }
  if (lane == 0) {
    const float cnt = (float)(B_*N_);
    float mu = s / cnt;
    float var = q / cnt - mu*mu;
    float al = bng[tf] * rsqrtf(var + EPS_);
    alpha[tf] = al;
    bet[tf] = bnb[tf] - mu*al;
  }
}

// ============ BN apply + pack to bf16 PRE-SWIZZLED sequence [t][b][320] ============
__global__ __launch_bounds__(256) void k_seq(
    const float* __restrict__ cheb, const float* __restrict__ alpha, const float* __restrict__ bet,
    __hip_bfloat16* __restrict__ seqb)
{
  int idx = blockIdx.x*256 + threadIdx.x;     // T*B*320
  int kp = idx % SEQP;                        // physical position
  int tb = idx / SEQP;
  int b = tb & (B_-1), t = tb >> 9;
  int sl = (kp >> 3) ^ (b & 7);               // logical slot
  int kl = sl*8 + (kp & 7);                   // logical element
  float v = 0.f;
  if (kl < NF_) v = cheb[(size_t)tb*NF_ + kl] * alpha[t*F_ + (kl % F_)] + bet[t*F_ + (kl % F_)];
  seqb[idx] = __float2bfloat16(v);
}

// ============ persistent LSTM (round-12 proven): 512-thr blocks, 16-block groups ============
#define WOP(M)  M(0) M(1) M(2) M(3) M(4) M(5) M(6) M(7) M(8) M(9) M(10) M(11) M(12) M(13) \
                M(14) M(15) M(16) M(17) M(18) M(19) M(20) M(21) M(22) M(23) M(24) M(25)
#define WSEQ(M) M(0) M(1) M(2) M(3) M(4) M(5) M(6) M(7) M(8) M(9)
#define WHP(M)  M(10) M(11) M(12) M(13) M(14) M(15) M(16) M(17) M(18) M(19) M(20) M(21) \
                M(22) M(23) M(24) M(25)

#define DECLW(i) short8 wv##i;
#define LOADW(i) wv##i = *(const short8*)(wp + (i)*32); \
                 asm volatile("" : "+v"(wv##i));
#define MFS(i) { const int ph = (((i)*4 + lhi) ^ key)*8; \
                 short8 x0 = *(const short8*)(lseq + rs0*SEQP + ph); \
                 short8 x1 = *(const short8*)(lseq + rs1*SEQP + ph); \
                 a0 = __builtin_amdgcn_mfma_f32_16x16x32_bf16(x0, wv##i, a0, 0, 0, 0); \
                 a1 = __builtin_amdgcn_mfma_f32_16x16x32_bf16(x1, wv##i, a1, 0, 0, 0); }
#define MFH(i) { const int ph = ((((i)-10)*4 + lhi) ^ key)*8; \
                 short8 x0 = *(const short8*)(lh + rs0*H_ + ph); \
                 short8 x1 = *(const short8*)(lh + rs1*H_ + ph); \
                 a0 = __builtin_amdgcn_mfma_f32_16x16x32_bf16(x0, wv##i, a0, 0, 0, 0); \
                 a1 = __builtin_amdgcn_mfma_f32_16x16x32_bf16(x1, wv##i, a1, 0, 0, 0); }

__global__ __launch_bounds__(512, 1) void k_lstm(
    const __hip_bfloat16* __restrict__ seqb,   // (T, B, 320) bf16, slot-swizzled
    const __hip_bfloat16* __restrict__ Wcat,   // (2048, 832) gate-interleaved
    const float* __restrict__ biasr,           // (2048)
    __hip_bfloat16* __restrict__ hb,           // (T, B, 512) bf16, slot-swizzled, write-once
    unsigned int* __restrict__ bar)            // (16*64) zeroed, rg-major flag words
{
  __shared__ __align__(16) short lh[32*H_];    // 32 KB: h panel
  __shared__ __align__(16) short lseq[32*SEQP];// 20 KB: seq panel
  __shared__ __align__(16) float gl[32][132];  // 16.5 KB: gate tile

  const int tid = threadIdx.x;
  const int bid = blockIdx.x;
  const int rg = bid & 15, jt = bid >> 4;      // jt in 0..15
  const int b0 = rg*32, j0 = jt*128;
  const int w = tid >> 6, lane = tid & 63, l16 = lane & 15, lhi = lane >> 4;
  const int key = l16 & 7;
  const int rs0 = l16, rs1 = l16 + 16;

  // ---- pin this wave's 26 weight fragments (col-tile = j0 + w*16) ----
  const short* wp = (const short*)Wcat + (size_t)(j0 + w*16 + l16)*KPAD + lhi*8;
  WOP(DECLW)
  WOP(LOADW)

  // cell mapping: 32 rows x 32 units; thread -> (crow = tid>>4, u2 = tid&15, 2 units)
  const int crow = tid >> 4, u2 = tid & 15;
  const int hrow = b0 + crow;
  float cc0 = 0.f, cc1 = 0.f;
  f32x4 biaA = *(const f32x4*)(biasr + j0 + u2*8 + 0);
  f32x4 biaB = *(const f32x4*)(biasr + j0 + u2*8 + 4);
  const int hslot = (jt*4 + (u2 >> 2)) ^ (hrow & 7);
  const int hoff = hslot*8 + (u2 & 3)*2;

  const char* gseq = (const char*)seqb;
  const char* ghb  = (const char*)hb;
  char* lsc = (char*)lseq;
  char* lhc = (char*)lh;

  // prologue: stage seq(0): 20KB contiguous
  {
    const char* gs = gseq + ((size_t)b0)*640;
    #pragma unroll
    for (int i = 0; i < 3; ++i) {
      int c = w + i*8;
      if (c < 20) dma16(gs + c*1024 + lane*16, lsc + c*1024);
    }
  }

  #pragma unroll 1
  for (int t = 0; t < T_; ++t) {
    // ---- wait for all 16 producers' flags >= t (parallel 16-lane probe) ----
    if (t > 0 && w == 0) {
      for (;;) {
        unsigned int v = 0xFFFFFFFFu;
        if (lane < 16)
          v = __hip_atomic_load(&bar[rg*64 + lane], __ATOMIC_RELAXED,
                                __HIP_MEMORY_SCOPE_AGENT);
        if (__all(v >= (unsigned int)t)) break;
        __builtin_amdgcn_s_sleep(1);
      }
    }
    __syncthreads();                           // (A) seq(t) staged; flags seen; prefetch drained

    if (t > 0) {                               // stage h(t-1): 32 x 1KB rows, 4 dma16/wave
      const char* gh = ghb + ((size_t)(t-1)*B_ + b0)*1024;
      #pragma unroll
      for (int i = 0; i < 4; ++i) {
        int c = w*4 + i;
        dma16(gh + c*1024 + lane*16, lhc + c*1024);
      }
    }

    // seq-part MFMAs (overlap h DMA)
    f32x4 a0 = {0.f,0.f,0.f,0.f}, a1 = a0;
    WSEQ(MFS)

    if (t > 0) {
      __syncthreads();                         // (B) h DMA drained (all waves)
      WHP(MFH)
    }

    #pragma unroll
    for (int r = 0; r < 4; ++r) {
      gl[     lhi*4 + r][w*16 + l16] = a0[r];
      gl[16 + lhi*4 + r][w*16 + l16] = a1[r];
    }
    __syncthreads();                           // (D) gl visible

    // cell update: 2 hidden units per thread
    {
      f32x4 ga = *(const f32x4*)(&gl[crow][u2*8 + 0]);
      f32x4 gb = *(const f32x4*)(&gl[crow][u2*8 + 4]);
      float iv0 = sigm(ga[0]+biaA[0]), fv0 = sigm(ga[1]+biaA[1]);
      float gv0 = tanhf_(ga[2]+biaA[2]), ov0 = sigm(ga[3]+biaA[3]);
      cc0 = fv0*cc0 + iv0*gv0;
      float h0 = ov0*tanhf_(cc0);
      float iv1 = sigm(gb[0]+biaB[0]), fv1 = sigm(gb[1]+biaB[1]);
      float gv1 = tanhf_(gb[2]+biaB[2]), ov1 = sigm(gb[3]+biaB[3]);
      cc1 = fv1*cc1 + iv1*gv1;
      float h1 = ov1*tanhf_(cc1);
      unsigned int d0;
      asm("v_cvt_pk_bf16_f32 %0, %1, %2" : "=v"(d0) : "v"(h0), "v"(h1));
      short* dst = (short*)hb + ((size_t)t*B_ + hrow)*H_ + hoff;
      asm volatile("global_store_dword %0, %1, off sc0 sc1"
                   :: "v"(dst), "v"(d0) : "memory");
    }
    __syncthreads();                           // (E) h stores drained (gl reads done too)

    if (t < T_ - 1) {
      if (tid == 0)                            // own flag word: plain store, no RMW
        __hip_atomic_store(&bar[rg*64 + jt], (unsigned int)(t+1),
                           __ATOMIC_RELAXED, __HIP_MEMORY_SCOPE_AGENT);
      const char* gs = gseq + ((size_t)(t+1)*B_ + b0)*640;
      #pragma unroll
      for (int i = 0; i < 3; ++i) {            // prefetch seq(t+1) OFF the critical path
        int c = w + i*8;
        if (c < 20) dma16(gs + c*1024 + lane*16, lsc + c*1024);
      }
    }
  }
}

// ============ BN1 partial stats over (B,H) per t — order-independent, swizzle-agnostic ============
__global__ __launch_bounds__(256) void k_bn1part(
    const __hip_bfloat16* __restrict__ hb, float* __restrict__ bn1s, float* __restrict__ bn1q)
{
  const int t = blockIdx.x, ch = blockIdx.y, tid = threadIdx.x;
  const short* base = (const short*)hb + ((size_t)t*B_ + ch*64)*H_;
  float s = 0.f, q = 0.f;
  for (int i = tid; i < 64*H_/8; i += 256) {
    short8 v8 = *(const short8*)(base + (i>>6)*H_ + (i&63)*8);
    #pragma unroll
    for (int j = 0; j < 8; ++j) { float v = b2f(v8[j]); s += v; q += v*v; }
  }
  __shared__ float rs[256], rq[256];
  rs[tid] = s; rq[tid] = q;
  __syncthreads();
  for (int o = 128; o; o >>= 1) {
    if (tid < o) { rs[tid] += rs[tid+o]; rq[tid] += rq[tid+o]; }
    __syncthreads();
  }
  if (tid == 0) { bn1s[t*8 + ch] = rs[0]; bn1q[t*8 + ch] = rq[0]; }
}

// ============ head: fold BN1 + (B, T*H) @ Wl^T + bl — unswizzles hbuf slots ============
__global__ __launch_bounds__(256) void k_head(
    const __hip_bfloat16* __restrict__ hb, const float* __restrict__ bn1s,
    const float* __restrict__ bn1q, const float* __restrict__ g1,
    const float* __restrict__ be1, const float* __restrict__ Wl,
    const float* __restrict__ bl, float* __restrict__ out)
{
  const int b = blockIdx.x, tid = threadIdx.x;
  __shared__ float al1[T_], bt1[T_];
  if (tid < T_) {
    float s = 0.f, q = 0.f;
    #pragma unroll
    for (int ch = 0; ch < 8; ++ch) { s += bn1s[tid*8 + ch]; q += bn1q[tid*8 + ch]; }
    const float cnt = (float)(B_*H_);
    float mu = s / cnt, var = q / cnt - mu*mu;
    float al = g1[tid] * rsqrtf(var + EPS_);
    al1[tid] = al; bt1[tid] = be1[tid] - mu*al;
  }
  __syncthreads();
  float a0 = 0.f, a1 = 0.f, a2 = 0.f;
  const short* hbs = (const short*)hb;
  for (int p8 = tid; p8 < T_*(H_/8); p8 += 256) {
    const int t = p8 >> 6, p = p8 & 63;
    short8 v8 = *(const short8*)(hbs + ((size_t)t*B_ + b)*H_ + p*8);
    const int wi = t*H_ + ((p ^ (b & 7)) << 3);
    #pragma unroll
    for (int j = 0; j < 8; ++j) {
      float yn = b2f(v8[j])*al1[t] + bt1[t];
      a0 = fmaf(yn, Wl[wi + j],            a0);
      a1 = fmaf(yn, Wl[T_*H_ + wi + j],    a1);
      a2 = fmaf(yn, Wl[2*T_*H_ + wi + j],  a2);
    }
  }
  __shared__ float red[256];
  red[tid] = a0; __syncthreads();
  for (int o = 128; o; o >>= 1) { if (tid < o) red[tid] += red[tid+o]; __syncthreads(); }
  if (!tid) out[b*3 + 0] = red[0] + bl[0];
  __syncthreads();
  red[tid] = a1; __syncthreads();
  for (int o = 128; o; o >>= 1) { if (tid < o) red[tid] += red[tid+o]; __syncthreads(); }
  if (!tid) out[b*3 + 1] = red[0] + bl[1];
  __syncthreads();
  red[tid] = a2; __syncthreads();
  for (int o = 128; o; o >>= 1) { if (tid < o) red[tid] += red[tid+o]; __syncthreads(); }
  if (!tid) out[b*3 + 2] = red[0] + bl[2];
}

extern "C" void kernel_launch(void* const* d_in, const int* in_sizes, int n_in,
                              void* d_out, int out_size, void* d_ws, size_t ws_size,
                              hipStream_t stream)
{
  (void)in_sizes; (void)n_in; (void)out_size;
  const float* x   = (const float*)d_in[0];
  const int* esrc  = (const int*)d_in[1];
  const int* edst  = (const int*)d_in[2];
  const float* ew  = (const float*)d_in[3];
  const float* Wc  = (const float*)d_in[4];
  const float* bc  = (const float*)d_in[5];
  const float* bng = (const float*)d_in[6];
  const float* bnb = (const float*)d_in[7];
  const float* Wih = (const float*)d_in[8];
  const float* Whh = (const float*)d_in[9];
  const float* bih = (const float*)d_in[10];
  const float* bhh = (const float*)d_in[11];
  const float* g1  = (const float*)d_in[12];
  const float* be1 = (const float*)d_in[13];
  const float* Wl  = (const float*)d_in[14];
  const float* bl  = (const float*)d_in[15];
  float* out = (float*)d_out;

  char* ws = (char*)d_ws;
  size_t off = 0;
  auto alloc = [&](size_t bytes) {
    void* p = ws + off;
    off += (bytes + 255) & ~(size_t)255;
    return p;
  };
  float* cheb = (float*)alloc(sizeof(float)*(size_t)T_*B_*NF_);
  float* bps  = (float*)alloc(sizeof(float)*T_*F_*B_);
  float* bpq  = (float*)alloc(sizeof(float)*T_*F_*B_);
  float* alpha= (float*)alloc(sizeof(float)*T_*F_);
  float* bet  = (float*)alloc(sizeof(float)*T_*F_);
  __hip_bfloat16* lap  = (__hip_bfloat16*)alloc(sizeof(__hip_bfloat16)*(size_t)B_*4096);
  __hip_bfloat16* seqb = (__hip_bfloat16*)alloc(sizeof(__hip_bfloat16)*(size_t)T_*B_*SEQP);
  __hip_bfloat16* Wcat = (__hip_bfloat16*)alloc(sizeof(__hip_bfloat16)*(size_t)G4*KPAD);
  float* biasr = (float*)alloc(sizeof(float)*G4);
  __hip_bfloat16* hbuf = (__hip_bfloat16*)alloc(sizeof(__hip_bfloat16)*(size_t)T_*B_*H_);
  float* bn1s = (float*)alloc(sizeof(float)*T_*8);
  float* bn1q = (float*)alloc(sizeof(float)*T_*8);
  unsigned int* bar = (unsigned int*)alloc(sizeof(unsigned int)*16*64);
  if (ws_size < off) return;   // ~80 MB — within proven budget

  (void)hipMemsetAsync(bar, 0, sizeof(unsigned int)*16*64, stream);

  k_lapprep<<<B_ + G4, 256, 0, stream>>>(esrc, edst, ew, Wih, Whh, bih, bhh, lap, Wcat, biasr);
  k_cheb<<<dim3(B_, T_/TC), 512, 0, stream>>>(x, lap, Wc, bc, cheb, bps, bpq);
  k_bnfin<<<T_*F_, 64, 0, stream>>>(bps, bpq, bng, bnb, alpha, bet);
  k_seq<<<(T_*B_*SEQP)/256, 256, 0, stream>>>(cheb, alpha, bet, seqb);

  k_lstm<<<256, 512, 0, stream>>>(seqb, Wcat, biasr, hbuf, bar);

  k_bn1part<<<dim3(T_, 8), 256, 0, stream>>>(hbuf, bn1s, bn1q);
  k_head<<<B_, 256, 0, stream>>>(hbuf, bn1s, bn1q, g1, be1, Wl, bl, out);
}